// Round 9
// baseline (476.446 us; speedup 1.0000x reference)
//
#include <hip/hip_runtime.h>
#include <cstdint>
#include <cstddef>

#define NH   16
#define HD   64
#define RLEN 2048
#define BSZ  2
#define SLEN 64
#define NZ   64
#define ED   1024
#define KTOT 2112   // SLEN + RLEN
#define NSPLIT 8    // sum_attn key splits
#define QSCALE 0.18033688011111374f   // 0.125 * log2(e) — softmax in log2 domain

typedef __bf16 bf16_t;
typedef bf16_t bf16x8 __attribute__((ext_vector_type(8)));
typedef bf16_t bf16x4 __attribute__((ext_vector_type(4)));
typedef float  f32x4  __attribute__((ext_vector_type(4)));

__device__ __forceinline__ f32x4 mfma16(bf16x8 a, bf16x8 b, f32x4 c) {
    return __builtin_amdgcn_mfma_f32_16x16x32_bf16(a, b, c, 0, 0, 0);
}

// async global->LDS DMA, 16B per lane (used by gemm_fast only)
__device__ __forceinline__ void dma16(const void* g, void* l) {
    __builtin_amdgcn_global_load_lds(
        (const __attribute__((address_space(1))) unsigned int*)g,
        (__attribute__((address_space(3))) unsigned int*)l, 16, 0, 0);
}

// Frag-major K layout per bh (PERMUTED keys: within a 64-key tile, MFMA
// group nt holds keys {4*l15+nt}):
//   off(key,d) = tile*4096 + (((key&3)*2 + (d>>5))*64 + ((d>>3)&3)*16 + ((key>>2)&15))*8 + (d&7)
// Frag-major V^T (natural key order): granule(dcol,key):
//   off(d,key) = tile*4096 + (((d>>4)*2 + (key>>5))*64 + ((key>>3)&3)*16 + (d&15))*8 + (key&7)

// ------------------------------------------------------------------
// m97-style GEMM: A bf16 [M][K], Bt bf16 [N][K]; BK=64, tile BM x 128,
// global_load_lds staging with XOR-swizzled granules.
// ------------------------------------------------------------------
template<int BM>
__global__ __launch_bounds__(256) void gemm_fast(
    const bf16_t* __restrict__ A, const bf16_t* __restrict__ Bt,
    const float* __restrict__ b0, const float* __restrict__ b1,
    const float* __restrict__ b2,
    bf16_t* __restrict__ oq, float* __restrict__ o1, float* __restrict__ o2,
    int M, int K, int N, int mode)
{
    constexpr int MT = BM / 64;
    __shared__ __align__(16) bf16_t As[BM * 64];
    __shared__ __align__(16) bf16_t Bs[128 * 64];

    const int t = threadIdx.x;
    const int wave = t >> 6, lane = t & 63;
    const int quad = lane >> 4, l15 = lane & 15;
    const int rsub = lane >> 3, gq = lane & 7;
    const int m0 = blockIdx.y * BM, n0 = blockIdx.x * 128;

    f32x4 acc[MT][8];
#pragma unroll
    for (int i = 0; i < MT; i++)
#pragma unroll
        for (int j = 0; j < 8; j++) acc[i][j] = (f32x4){0.f, 0.f, 0.f, 0.f};

    for (int k0 = 0; k0 < K; k0 += 64) {
#pragma unroll
        for (int j = 0; j < BM / 32; j++) {
            int row = wave * (BM / 4) + j * 8 + rsub;
            const bf16_t* g = A + (size_t)(m0 + row) * K + k0 + ((gq ^ (row & 7)) * 8);
            dma16(g, As + (wave * (BM / 4) + j * 8) * 64);
        }
#pragma unroll
        for (int j = 0; j < 4; j++) {
            int row = wave * 32 + j * 8 + rsub;
            const bf16_t* g = Bt + (size_t)(n0 + row) * K + k0 + ((gq ^ (row & 7)) * 8);
            dma16(g, Bs + (wave * 32 + j * 8) * 64);
        }
        __syncthreads();

#pragma unroll
        for (int kk = 0; kk < 2; kk++) {
            const int pg = ((kk * 4 + quad) ^ (l15 & 7)) * 8;
            bf16x8 af[MT], bf[8];
#pragma unroll
            for (int mt = 0; mt < MT; mt++)
                af[mt] = *(const bf16x8*)(As + (wave * (BM / 4) + mt * 16 + l15) * 64 + pg);
#pragma unroll
            for (int nt = 0; nt < 8; nt++)
                bf[nt] = *(const bf16x8*)(Bs + (nt * 16 + l15) * 64 + pg);
#pragma unroll
            for (int mt = 0; mt < MT; mt++)
#pragma unroll
                for (int nt = 0; nt < 8; nt++)
                    acc[mt][nt] = mfma16(af[mt], bf[nt], acc[mt][nt]);
        }
        __syncthreads();
    }

#pragma unroll
    for (int mt = 0; mt < MT; mt++)
#pragma unroll
        for (int nt = 0; nt < 8; nt++)
#pragma unroll
            for (int reg = 0; reg < 4; reg++) {
                int m = m0 + wave * (BM / 4) + mt * 16 + quad * 4 + reg;
                int n = n0 + nt * 16 + l15;
                if (mode == 0) {
                    o1[(size_t)m * N + n] = acc[mt][nt][reg] + b0[n];
                } else {
                    int seg = n >> 10, nl = n & 1023;
                    const float* bias = (seg == 0) ? b0 : (seg == 1) ? b1 : b2;
                    float c = acc[mt][nt][reg] + bias[nl];
                    int h = nl >> 6, d = nl & 63;
                    int r = m >> 1, bb = m & 1;
                    size_t off = (((size_t)bb * NH + h) * RLEN + r) * HD + d;
                    if (seg == 0)      oq[off] = (bf16_t)(c * QSCALE);
                    else if (seg == 1) o1[off] = c;
                    else               o2[off] = c;
                }
            }
}

// ------------------------------------------------------------------
// 64x128 MFMA GEMM (small r0 gemm only), padded LDS.
// ------------------------------------------------------------------
__global__ __launch_bounds__(256) void gemm_mfma(
    const bf16_t* __restrict__ A, const bf16_t* __restrict__ Bt,
    const float* __restrict__ bias, float* __restrict__ outf,
    int M, int K, int N, int Rr)
{
    constexpr int LDA = 40;
    __shared__ __align__(16) bf16_t As[64 * LDA];
    __shared__ __align__(16) bf16_t Bs[128 * LDA];

    const int t = threadIdx.x;
    const int wave = t >> 6, lane = t & 63;
    const int quad = lane >> 4, l15 = lane & 15;
    const int wrow = wave >> 1, wcol = wave & 1;
    const int m0 = blockIdx.y * 64, n0 = blockIdx.x * 128;

    f32x4 acc[2][4];
#pragma unroll
    for (int i = 0; i < 2; i++)
#pragma unroll
        for (int j = 0; j < 4; j++) acc[i][j] = (f32x4){0.f, 0.f, 0.f, 0.f};

    const int srow = t >> 2, sseg = (t & 3) * 8;

    for (int k0 = 0; k0 < K; k0 += 32) {
        bf16x8 av  = *(const bf16x8*)(A  + (size_t)(m0 + srow) * K + k0 + sseg);
        bf16x8 bv0 = *(const bf16x8*)(Bt + (size_t)(n0 + srow) * K + k0 + sseg);
        bf16x8 bv1 = *(const bf16x8*)(Bt + (size_t)(n0 + 64 + srow) * K + k0 + sseg);
        __syncthreads();
        *(bf16x8*)(As + srow * LDA + sseg)        = av;
        *(bf16x8*)(Bs + srow * LDA + sseg)        = bv0;
        *(bf16x8*)(Bs + (64 + srow) * LDA + sseg) = bv1;
        __syncthreads();

        bf16x8 af[2], bf[4];
#pragma unroll
        for (int mt = 0; mt < 2; mt++)
            af[mt] = *(const bf16x8*)(As + (wrow * 32 + mt * 16 + l15) * LDA + quad * 8);
#pragma unroll
        for (int nt = 0; nt < 4; nt++)
            bf[nt] = *(const bf16x8*)(Bs + (wcol * 64 + nt * 16 + l15) * LDA + quad * 8);
#pragma unroll
        for (int mt = 0; mt < 2; mt++)
#pragma unroll
            for (int nt = 0; nt < 4; nt++)
                acc[mt][nt] = mfma16(af[mt], bf[nt], acc[mt][nt]);
    }

#pragma unroll
    for (int mt = 0; mt < 2; mt++)
#pragma unroll
        for (int nt = 0; nt < 4; nt++)
#pragma unroll
            for (int reg = 0; reg < 4; reg++) {
                int m = m0 + wrow * 32 + mt * 16 + quad * 4 + reg;
                int n = n0 + wcol * 64 + nt * 16 + l15;
                if (m >= M) continue;
                float c = acc[mt][nt][reg] + bias[n];
                int h = n >> 6, d = n & 63;
                outf[(((size_t)h) * Rr + m) * HD + d] = c;   // [h][z][d]
            }
}

// ------------------------------------------------------------------
// K LayerNorm -> frag-major bf16 (PERMUTED keys). One wave per key row.
// ------------------------------------------------------------------
__global__ __launch_bounds__(256) void ln_k_frag(
    const float* __restrict__ x, const float* __restrict__ g, const float* __restrict__ b,
    bf16_t* __restrict__ kfm)
{
    int row  = blockIdx.x * 4 + (threadIdx.x >> 6);
    int lane = threadIdx.x & 63;
    float v = x[(size_t)row * HD + lane];
    float s1 = v, s2 = v * v;
#pragma unroll
    for (int o = 32; o > 0; o >>= 1) {
        s1 += __shfl_xor(s1, o);
        s2 += __shfl_xor(s2, o);
    }
    float mean = s1 * (1.f / 64.f);
    float var  = s2 * (1.f / 64.f) - mean * mean;
    float y = (v - mean) * rsqrtf(var + 1e-5f) * g[lane] + b[lane];
    int bh = row >> 11, r = row & 2047, d = lane;
    int rt = r & 63;
    size_t off = (size_t)bh * 131072 + (size_t)(r >> 6) * 4096 +
        (size_t)((((rt & 3) * 2 + (d >> 5)) * 64 + ((d >> 3) & 3) * 16 + (rt >> 2)) * 8 + (d & 7));
    kfm[off] = (bf16_t)y;
}

// ------------------------------------------------------------------
// V LayerNorm + transpose -> frag-major bf16 V^T (natural key order).
// ------------------------------------------------------------------
__global__ __launch_bounds__(256) void lnv_frag(
    const float* __restrict__ v, const float* __restrict__ g,
    const float* __restrict__ b, bf16_t* __restrict__ vfm)
{
    __shared__ float tile[64][65];
    const int bh = blockIdx.y, tidx = blockIdx.x;
    const int t = threadIdx.x;
    const int wave = t >> 6, lane = t & 63;

#pragma unroll
    for (int i = 0; i < 16; i++) {
        int rl = wave * 16 + i;
        float x = v[((size_t)bh * RLEN + tidx * 64 + rl) * HD + lane];
        float s1 = x, s2 = x * x;
#pragma unroll
        for (int o = 32; o > 0; o >>= 1) {
            s1 += __shfl_xor(s1, o);
            s2 += __shfl_xor(s2, o);
        }
        float mean = s1 * (1.f / 64.f);
        float var  = s2 * (1.f / 64.f) - mean * mean;
        tile[rl][lane] = (x - mean) * rsqrtf(var + 1e-5f) * g[lane] + b[lane];
    }
    __syncthreads();
    int d = t >> 2, rs = (t & 3) * 16;
    bf16x8 o0, o1;
#pragma unroll
    for (int j = 0; j < 8; j++) {
        o0[j] = (bf16_t)tile[rs + j][d];
        o1[j] = (bf16_t)tile[rs + 8 + j][d];
    }
    size_t base = (size_t)bh * 131072;
    size_t off0 = base + (size_t)((((tidx * 4 + (d >> 4)) * 2 + (rs >> 5)) * 64
                  + ((rs >> 3) & 3) * 16 + (d & 15)) * 8);
    int rs2 = rs + 8;
    size_t off1 = base + (size_t)((((tidx * 4 + (d >> 4)) * 2 + (rs2 >> 5)) * 64
                  + ((rs2 >> 3) & 3) * 16 + (d & 15)) * 8);
    *(bf16x8*)(vfm + off0) = o0;
    *(bf16x8*)(vfm + off1) = o1;
}

// ------------------------------------------------------------------
__global__ __launch_bounds__(256) void cvt_bf16(
    const float* __restrict__ src, bf16_t* __restrict__ dst, int n)
{
    int i = (blockIdx.x * 256 + threadIdx.x) * 4;
    if (i < n) {
        float4 v = *(const float4*)(src + i);
        bf16x4 o;
        o[0] = (bf16_t)v.x; o[1] = (bf16_t)v.y; o[2] = (bf16_t)v.z; o[3] = (bf16_t)v.w;
        *(bf16x4*)(dst + i) = o;
    }
}

// ------------------------------------------------------------------
// Prep kernel: batched weight transpose+cvt (bids 0..1039), sum_q
// gather (1040..1167), rel_emb0 cvt (1168..1171).
// ------------------------------------------------------------------
__global__ __launch_bounds__(256) void prep_batch(
    const float* __restrict__ Wq, const float* __restrict__ Wk,
    const float* __restrict__ Wv, const float* __restrict__ Wo,
    const float* __restrict__ Wr0,
    bf16_t* __restrict__ wqt, bf16_t* __restrict__ wkt,
    bf16_t* __restrict__ wvt, bf16_t* __restrict__ wot,
    bf16_t* __restrict__ wr0t,
    const float* __restrict__ emb, const int* __restrict__ ids,
    bf16_t* __restrict__ sum_q,
    const float* __restrict__ rel_emb0, bf16_t* __restrict__ re0b)
{
    const int bid = blockIdx.x;
    const int t = threadIdx.x;

    if (bid >= 1168) {          // rel_emb0 cvt (4096 elems)
        int i = ((bid - 1168) * 256 + t) * 4;
        float4 v = *(const float4*)(rel_emb0 + i);
        bf16x4 o;
        o[0] = (bf16_t)v.x; o[1] = (bf16_t)v.y; o[2] = (bf16_t)v.z; o[3] = (bf16_t)v.w;
        *(bf16x4*)(re0b + i) = o;
        return;
    }
    if (bid >= 1040) {          // sum_q gather (log2-domain scale)
        int sb = bid - 1040;
        int s = sb >> 1, b = sb & 1;
        int id = ids[b * SLEN + s];
        const float* src = emb + (size_t)id * ED;
        for (int e = t; e < ED; e += 256) {
            int h = e >> 6, d = e & 63;
            sum_q[(((size_t)b * NH + h) * SLEN + s) * HD + d] = (bf16_t)(src[e] * QSCALE);
        }
        return;
    }

    __shared__ float tile[64][65];
    const float* src; bf16_t* dst; int R, C, r0, c0;
    if (bid < 1024) {
        int sel = bid >> 8, local = bid & 255;
        src = (sel == 0) ? Wq : (sel == 1) ? Wk : (sel == 2) ? Wv : Wo;
        dst = (sel == 0) ? wqt : (sel == 1) ? wkt : (sel == 2) ? wvt : wot;
        R = ED; C = ED; r0 = (local >> 4) * 64; c0 = (local & 15) * 64;
    } else {
        src = Wr0; dst = wr0t; R = NZ; C = ED; r0 = 0; c0 = (bid - 1024) * 64;
    }
#pragma unroll
    for (int i = 0; i < 4; i++) {
        int idx = t + i * 256;
        int r = idx >> 4, c = (idx & 15) * 4;
        float4 vv = *(const float4*)(src + (size_t)(r0 + r) * C + c0 + c);
        tile[r][c] = vv.x; tile[r][c + 1] = vv.y; tile[r][c + 2] = vv.z; tile[r][c + 3] = vv.w;
    }
    __syncthreads();
    int cc = t >> 2, rs = (t & 3) * 16;
    bf16x8 o0, o1;
#pragma unroll
    for (int j = 0; j < 8; j++) {
        o0[j] = (bf16_t)tile[rs + j][cc];
        o1[j] = (bf16_t)tile[rs + 8 + j][cc];
    }
    *(bf16x8*)(dst + (size_t)(c0 + cc) * R + r0 + rs) = o0;
    *(bf16x8*)(dst + (size_t)(c0 + cc) * R + r0 + rs + 8) = o1;
}

// ------------------------------------------------------------------
// One 64-key attention tile for a wave owning MT*16 q-rows.
// Barrier-free. Softmax in log2 domain (scores pre-scaled by log2e):
// shared quad-group max, row sums via MFMA with all-ones B operand.
// ------------------------------------------------------------------
template<int MT>
__device__ __forceinline__ void attn_tile(
    const bf16_t* __restrict__ kt, const bf16_t* __restrict__ vt,
    const int* __restrict__ relbase, int koff, bool userel,
    const float* __restrict__ qrsw, bf16_t* __restrict__ Psw,
    const bf16x8 (&qf)[MT][2],
    f32x4 (&O)[MT][4], float& m_q, float (&l_i)[MT][4],
    int quad, int l15, int lane)
{
    bf16x8 kf[4][2];
#pragma unroll
    for (int nt = 0; nt < 4; nt++)
#pragma unroll
        for (int kb = 0; kb < 2; kb++)
            kf[nt][kb] = *(const bf16x8*)(kt + ((nt * 2 + kb) * 64 + lane) * 8);

    int4 crel[MT][4];
    if (userel) {
#pragma unroll
        for (int mt = 0; mt < MT; mt++)
#pragma unroll
            for (int reg = 0; reg < 4; reg++)
                crel[mt][reg] = *(const int4*)(relbase + (size_t)(mt * 16 + reg) * RLEN + koff);
    }

    f32x4 S[MT][4];
#pragma unroll
    for (int mt = 0; mt < MT; mt++)
#pragma unroll
        for (int nt = 0; nt < 4; nt++) {
            f32x4 acc = (f32x4){0.f, 0.f, 0.f, 0.f};
            acc = mfma16(qf[mt][0], kf[nt][0], acc);
            acc = mfma16(qf[mt][1], kf[nt][1], acc);
            S[mt][nt] = acc;
        }

    // V frags issued now (K regs dead) — latency hides under softmax
    bf16x8 vf[4][2];
#pragma unroll
    for (int nt = 0; nt < 4; nt++)
#pragma unroll
        for (int kb = 0; kb < 2; kb++)
            vf[nt][kb] = *(const bf16x8*)(vt + ((nt * 2 + kb) * 64 + lane) * 8);

    if (userel) {
#pragma unroll
        for (int mt = 0; mt < MT; mt++)
#pragma unroll
            for (int reg = 0; reg < 4; reg++) {
                const float* qr = qrsw + (mt * 16 + quad * 4 + reg) * 64;
                int4 c = crel[mt][reg];
                S[mt][0][reg] += qr[c.x];
                S[mt][1][reg] += qr[c.y];
                S[mt][2][reg] += qr[c.z];
                S[mt][3][reg] += qr[c.w];
            }
    }

    // shared quad-group max: one shuffle chain for all MT*4 rows
    float v = -1e30f;
#pragma unroll
    for (int mt = 0; mt < MT; mt++)
#pragma unroll
        for (int nt = 0; nt < 4; nt++) {
            f32x4 s = S[mt][nt];
            v = fmaxf(v, fmaxf(fmaxf(s[0], s[1]), fmaxf(s[2], s[3])));
        }
#pragma unroll
    for (int o = 8; o > 0; o >>= 1) v = fmaxf(v, __shfl_xor(v, o));
    float mnew = fmaxf(m_q, v);
    float alpha = exp2f(m_q - mnew);
    m_q = mnew;

#pragma unroll
    for (int mt = 0; mt < MT; mt++)
#pragma unroll
        for (int nt = 0; nt < 4; nt++)
#pragma unroll
            for (int reg = 0; reg < 4; reg++)
                S[mt][nt][reg] = exp2f(S[mt][nt][reg] - mnew);

#pragma unroll
    for (int mt = 0; mt < MT; mt++) {
#pragma unroll
        for (int nt = 0; nt < 4; nt++) {
            O[mt][nt][0] *= alpha; O[mt][nt][1] *= alpha;
            O[mt][nt][2] *= alpha; O[mt][nt][3] *= alpha;
        }
#pragma unroll
        for (int reg = 0; reg < 4; reg++) l_i[mt][reg] *= alpha;
    }

    // P -> LDS (4 consecutive keys per lane), PV + row-sum via MFMA-ones
    bf16x8 ones;
#pragma unroll
    for (int j = 0; j < 8; j++) ones[j] = (bf16_t)1.0f;

#pragma unroll
    for (int mt = 0; mt < MT; mt++)
#pragma unroll
        for (int reg = 0; reg < 4; reg++) {
            bf16x4 pv;
            pv[0] = (bf16_t)S[mt][0][reg]; pv[1] = (bf16_t)S[mt][1][reg];
            pv[2] = (bf16_t)S[mt][2][reg]; pv[3] = (bf16_t)S[mt][3][reg];
            *(bf16x4*)(Psw + (mt * 16 + quad * 4 + reg) * 72 + 4 * l15) = pv;
        }

#pragma unroll
    for (int mt = 0; mt < MT; mt++) {
        bf16x8 pf0 = *(const bf16x8*)(Psw + (mt * 16 + l15) * 72 + quad * 8);
        bf16x8 pf1 = *(const bf16x8*)(Psw + (mt * 16 + l15) * 72 + 32 + quad * 8);
        f32x4 ls = (f32x4){0.f, 0.f, 0.f, 0.f};
        ls = mfma16(pf0, ones, ls);
        ls = mfma16(pf1, ones, ls);
#pragma unroll
        for (int nt = 0; nt < 4; nt++) {
            O[mt][nt] = mfma16(pf0, vf[nt][0], O[mt][nt]);
            O[mt][nt] = mfma16(pf1, vf[nt][1], O[mt][nt]);
        }
#pragma unroll
        for (int reg = 0; reg < 4; reg++) l_i[mt][reg] += ls[reg];
    }
}

// build fp32 qr table rows (mt*16 + quad*4 + reg) for this wave
template<int MT>
__device__ __forceinline__ void build_qr(
    const float* __restrict__ r0, int h, const bf16x8 (&qf)[MT][2],
    float* __restrict__ qrsw, int quad, int l15)
{
#pragma unroll
    for (int nt = 0; nt < 4; nt++) {
        const float* rp = r0 + ((size_t)h * NZ + l15 + 16 * nt) * HD + quad * 8;
        float4 a0 = *(const float4*)(rp);
        float4 a1 = *(const float4*)(rp + 4);
        bf16x8 bf0;
        bf0[0] = (bf16_t)a0.x; bf0[1] = (bf16_t)a0.y; bf0[2] = (bf16_t)a0.z; bf0[3] = (bf16_t)a0.w;
        bf0[4] = (bf16_t)a1.x; bf0[5] = (bf16_t)a1.y; bf0[6] = (bf16_t)a1.z; bf0[7] = (bf16_t)a1.w;
        float4 b0 = *(const float4*)(rp + 32);
        float4 b1 = *(const float4*)(rp + 36);
        bf16x8 bf1;
        bf1[0] = (bf16_t)b0.x; bf1[1] = (bf16_t)b0.y; bf1[2] = (bf16_t)b0.z; bf1[3] = (bf16_t)b0.w;
        bf1[4] = (bf16_t)b1.x; bf1[5] = (bf16_t)b1.y; bf1[6] = (bf16_t)b1.z; bf1[7] = (bf16_t)b1.w;
#pragma unroll
        for (int mt = 0; mt < MT; mt++) {
            f32x4 qa = (f32x4){0.f, 0.f, 0.f, 0.f};
            qa = mfma16(qf[mt][0], bf0, qa);
            qa = mfma16(qf[mt][1], bf1, qa);
#pragma unroll
            for (int reg = 0; reg < 4; reg++)
                qrsw[(mt * 16 + quad * 4 + reg) * 64 + l15 + 16 * nt] = qa[reg];
        }
    }
}

// ------------------------------------------------------------------
// Summary attention, split-K, barrier-free. grid (32, NSPLIT).
// ------------------------------------------------------------------
__global__ __launch_bounds__(256) void sum_attn_split(
    const bf16_t* __restrict__ Qb,   // sum_q [bh][s][d] row-major
    const bf16_t* __restrict__ kfm, const bf16_t* __restrict__ vfm,
    const float*  __restrict__ r0,
    const int*    __restrict__ rel_idx,
    float* __restrict__ po, float* __restrict__ pm, float* __restrict__ pl)
{
    const int bh = blockIdx.x;
    const int split = blockIdx.y;
    const int b = bh >> 4, h = bh & 15;
    const int t = threadIdx.x;
    const int wave = t >> 6, lane = t & 63;
    const int quad = lane >> 4, l15 = lane & 15;

    __shared__ __align__(16) bf16_t Ps[4][16 * 72];
    __shared__ float qrs[4][16 * 64];

    bf16x8 qf[1][2];
    const bf16_t* Qrow = Qb + ((size_t)bh * SLEN + wave * 16 + l15) * HD;
    qf[0][0] = *(const bf16x8*)(Qrow + quad * 8);
    qf[0][1] = *(const bf16x8*)(Qrow + 32 + quad * 8);

    build_qr<1>(r0, h, qf, qrs[wave], quad, l15);

    f32x4 O[1][4];
    float m_q = -1e30f;
    float l_i[1][4];
#pragma unroll
    for (int nt = 0; nt < 4; nt++) O[0][nt] = (f32x4){0.f, 0.f, 0.f, 0.f};
#pragma unroll
    for (int r = 0; r < 4; r++) l_i[0][r] = 0.f;

    const int* relbase = rel_idx + ((size_t)b * KTOT + wave * 16 + quad * 4) * RLEN + 4 * l15;

    const bf16_t* kbase = kfm + (size_t)bh * 131072 + (size_t)(split * 4) * 4096;
    const bf16_t* vbase = vfm + (size_t)bh * 131072 + (size_t)(split * 4) * 4096;

    for (int i = 0; i < 4; i++) {
        const int koff = (split * 4 + i) * 64;
        attn_tile<1>(kbase + (size_t)i * 4096, vbase + (size_t)i * 4096,
                     relbase, koff, true, qrs[wave], Ps[wave], qf,
                     O, m_q, l_i, quad, l15, lane);
    }

    const size_t pslot = (size_t)bh * NSPLIT + split;
#pragma unroll
    for (int nt = 0; nt < 4; nt++)
#pragma unroll
        for (int reg = 0; reg < 4; reg++) {
            int sq = wave * 16 + quad * 4 + reg;
            po[(pslot * SLEN + sq) * HD + l15 + 16 * nt] = O[0][nt][reg];
        }
#pragma unroll
    for (int reg = 0; reg < 4; reg++) {
        int sq = wave * 16 + quad * 4 + reg;
        if (l15 == 0) {
            pm[pslot * SLEN + sq] = m_q;
            pl[pslot * SLEN + sq] = l_i[0][reg];
        }
    }
}

// ------------------------------------------------------------------
// Fused split-reduce + sum_k2/sum_v2 LN projections. One wave per
// (bh, s) row. grid 2048 x 64 threads. (pm is in log2 domain.)
// ------------------------------------------------------------------
__global__ __launch_bounds__(64) void k2v2_fused(
    const float* __restrict__ po, const float* __restrict__ pm,
    const float* __restrict__ pl,
    const float* __restrict__ Wk2, const float* __restrict__ bk2,
    const float* __restrict__ Wv2, const float* __restrict__ bv2,
    const float* __restrict__ gk, const float* __restrict__ bk,
    const float* __restrict__ gv, const float* __restrict__ bv,
    bf16_t* __restrict__ k2fm, bf16_t* __restrict__ v2fm)
{
    int row = blockIdx.x;              // bh*64 + s
    int d = threadIdx.x;
    int bh = row >> 6, s = row & 63;

    // reduce splits for this row (log2 domain)
    float M = -1e30f, mm[NSPLIT];
#pragma unroll
    for (int j = 0; j < NSPLIT; j++) {
        mm[j] = pm[((size_t)bh * NSPLIT + j) * SLEN + s];
        M = fmaxf(M, mm[j]);
    }
    float L = 0.f, acc = 0.f;
#pragma unroll
    for (int j = 0; j < NSPLIT; j++) {
        float a = exp2f(mm[j] - M);
        L += pl[((size_t)bh * NSPLIT + j) * SLEN + s] * a;
        acc += po[(((size_t)bh * NSPLIT + j) * SLEN + s) * HD + d] * a;
    }
    __shared__ float xs[64];
    xs[d] = acc / L;
    __syncthreads();

#pragma unroll
    for (int which = 0; which < 2; which++) {
        const float* W  = which ? Wv2 : Wk2;
        const float* bi = which ? bv2 : bk2;
        const float* g  = which ? gv : gk;
        const float* bb = which ? bv : bk;
        float a = bi[d];
#pragma unroll
        for (int j = 0; j < 64; j++) a += xs[j] * W[j * HD + d];
        float s1 = a, s2 = a * a;
#pragma unroll
        for (int o = 32; o > 0; o >>= 1) {
            s1 += __shfl_xor(s1, o);
            s2 += __shfl_xor(s2, o);
        }
        float mean = s1 * (1.f / 64.f);
        float var  = s2 * (1.f / 64.f) - mean * mean;
        float y = (a - mean) * rsqrtf(var + 1e-5f) * g[d] + bb[d];
        if (which == 0) {
            size_t off = (size_t)bh * 4096 +
                (size_t)((((s & 3) * 2 + (d >> 5)) * 64
                          + ((d >> 3) & 3) * 16 + (s >> 2)) * 8 + (d & 7));
            k2fm[off] = (bf16_t)y;
        } else {
            size_t off = (size_t)bh * 4096 +
                (size_t)((((d >> 4) * 2 + (s >> 5)) * 64
                          + ((s >> 3) & 3) * 16 + (d & 15)) * 8 + (s & 7));
            v2fm[off] = (bf16_t)y;
        }
    }
}

// ------------------------------------------------------------------
// Main attention, barrier-free MFMA flash. Each wave owns 32 q-rows
// (2 m-frags), streams all 33 key-tiles global->reg. grid 512.
// ------------------------------------------------------------------
__global__ __launch_bounds__(256) void reg_attn_mfma(
    const bf16_t* __restrict__ Qb,    // [bh][r][d] row-major
    const bf16_t* __restrict__ kfm, const bf16_t* __restrict__ vfm,
    const bf16_t* __restrict__ k2fm, const bf16_t* __restrict__ v2fm,
    const float*  __restrict__ r0,
    const int*    __restrict__ rel_idx,
    bf16_t* __restrict__ attn_out)    // [r][b][E] bf16
{
    const int bid = blockIdx.x;       // 512 = 8 XCD x 4 bh x 16 qtiles
    const int bh = (bid & 7) * 4 + ((bid >> 3) & 3);
    const int qt = bid >> 5;          // 0..15
    const int b = bh >> 4, h = bh & 15;
    const int q0 = qt * 128;

    const int t = threadIdx.x;
    const int wave = t >> 6, lane = t & 63;
    const int quad = lane >> 4, l15 = lane & 15;

    __shared__ __align__(16) bf16_t Ps[4][32 * 72];
    __shared__ float qrs[4][32 * 64];

    bf16x8 qf[2][2];
#pragma unroll
    for (int mt = 0; mt < 2; mt++) {
        const bf16_t* Qrow = Qb + ((size_t)bh * RLEN + q0 + wave * 32 + mt * 16 + l15) * HD;
        qf[mt][0] = *(const bf16x8*)(Qrow + quad * 8);
        qf[mt][1] = *(const bf16x8*)(Qrow + 32 + quad * 8);
    }

    build_qr<2>(r0, h, qf, qrs[wave], quad, l15);

    f32x4 O[2][4];
    float m_q = -1e30f;
    float l_i[2][4];
#pragma unroll
    for (int mt = 0; mt < 2; mt++)
#pragma unroll
        for (int nt = 0; nt < 4; nt++) O[mt][nt] = (f32x4){0.f, 0.f, 0.f, 0.f};
#pragma unroll
    for (int mt = 0; mt < 2; mt++)
#pragma unroll
        for (int r = 0; r < 4; r++) l_i[mt][r] = 0.f;

    const int* relbase = rel_idx +
        ((size_t)b * KTOT + SLEN + q0 + wave * 32 + quad * 4) * RLEN + 4 * l15;

    // summary tile (no rel bias), peeled
    attn_tile<2>(k2fm + (size_t)bh * 4096, v2fm + (size_t)bh * 4096,
                 relbase, 0, false, qrs[wave], Ps[wave], qf,
                 O, m_q, l_i, quad, l15, lane);

    const bf16_t* kt = kfm + (size_t)bh * 131072;
    const bf16_t* vt = vfm + (size_t)bh * 131072;
#pragma unroll 2
    for (int tile = 0; tile < 32; tile++) {
        attn_tile<2>(kt, vt, relbase, tile * 64, true,
                     qrs[wave], Ps[wave], qf, O, m_q, l_i, quad, l15, lane);
        kt += 4096; vt += 4096;
    }

#pragma unroll
    for (int mt = 0; mt < 2; mt++) {
        float linv[4];
#pragma unroll
        for (int reg = 0; reg < 4; reg++) linv[reg] = 1.0f / l_i[mt][reg];
#pragma unroll
        for (int nt = 0; nt < 4; nt++)
#pragma unroll
            for (int reg = 0; reg < 4; reg++) {
                int q = q0 + wave * 32 + mt * 16 + quad * 4 + reg;
                attn_out[((size_t)q * BSZ + b) * ED + h * HD + l15 + 16 * nt] =
                    (bf16_t)(O[mt][nt][reg] * linv[reg]);
            }
    }
}

// ------------------------------------------------------------------
extern "C" void kernel_launch(void* const* d_in, const int* in_sizes, int n_in,
                              void* d_out, int out_size, void* d_ws, size_t ws_size,
                              hipStream_t stream)
{
    const float* reg_x    = (const float*)d_in[0];
    const int*   sum_ids  = (const int*)d_in[1];
    const int*   rel_idx  = (const int*)d_in[2];
    const float* emb_sum  = (const float*)d_in[5];
    const float* rel_emb0 = (const float*)d_in[6];
    const float* Wq = (const float*)d_in[7];
    const float* bq = (const float*)d_in[8];
    const float* Wk = (const float*)d_in[9];
    const float* bk = (const float*)d_in[10];
    const float* Wv = (const float*)d_in[11];
    const float* bv = (const float*)d_in[12];
    const float* Wr0 = (const float*)d_in[13];
    const float* br0 = (const float*)d_in[14];
    const float* Wk2 = (const float*)d_in[15];
    const float* bk2 = (const float*)d_in[16];
    const float* Wv2 = (const float*)d_in[17];
    const float* bv2 = (const float*)d_in[18];
    const float* Wo  = (const float*)d_in[19];
    const float* bo  = (const float*)d_in[20];
    const float* ln_k_g  = (const float*)d_in[21];
    const float* ln_k_b  = (const float*)d_in[22];
    const float* ln_v_g  = (const float*)d_in[23];
    const float* ln_v_b  = (const float*)d_in[24];
    const float* ln_k2_g = (const float*)d_in[25];
    const float* ln_k2_b = (const float*)d_in[26];
    const float* ln_v2_g = (const float*)d_in[27];
    const float* ln_v2_b = (const float*)d_in[28];

    const size_t QKV = (size_t)BSZ * NH * RLEN * HD;   // 4,194,304
    const size_t SUM = (size_t)BSZ * NH * SLEN * HD;   // 131,072

    float* ws  = (float*)d_ws;
    float* k   = ws;                    // fp32 K; later aliased by aob
    float* v   = k + QKV;               // fp32 V
    float* r0  = v + QKV;

    bf16_t* xb   = (bf16_t*)(r0 + (size_t)NH * NZ * HD);  // dead after QKV -> po
    bf16_t* qb   = xb + QKV;
    bf16_t* kfm  = qb + QKV;
    bf16_t* vfm  = kfm + QKV;
    bf16_t* sqb  = vfm + QKV;
    bf16_t* k2fm = sqb + SUM;
    bf16_t* v2fm = k2fm + SUM;
    bf16_t* wqt  = v2fm + SUM;          // wqt|wkt|wvt contiguous [3072][1024]
    bf16_t* wkt  = wqt + (size_t)ED * ED;
    bf16_t* wvt  = wkt + (size_t)ED * ED;
    bf16_t* wot  = wvt + (size_t)ED * ED;
    bf16_t* wr0t = wot + (size_t)ED * ED;
    bf16_t* re0b = wr0t + (size_t)ED * NZ;
    bf16_t* aob  = (bf16_t*)k;
    float*  po   = (float*)xb;
    float*  pm   = po + (size_t)BSZ * NH * NSPLIT * SLEN * HD;
    float*  pl   = pm + (size_t)BSZ * NH * NSPLIT * SLEN;

    const int M = RLEN * BSZ;   // 4096

    cvt_bf16<<<(int)(QKV / 1024), 256, 0, stream>>>(reg_x, xb, (int)QKV);
    prep_batch<<<1172, 256, 0, stream>>>(Wq, Wk, Wv, Wo, Wr0,
                                         wqt, wkt, wvt, wot, wr0t,
                                         emb_sum, sum_ids, sqb, rel_emb0, re0b);

    gemm_fast<128><<<dim3(3 * ED / 128, M / 128), 256, 0, stream>>>(
        xb, wqt, bq, bk, bv, qb, k, v, M, ED, 3 * ED, 1);

    ln_k_frag<<<(BSZ * NH * RLEN) / 4, 256, 0, stream>>>(k, ln_k_g, ln_k_b, kfm);
    lnv_frag<<<dim3(RLEN / 64, BSZ * NH), 256, 0, stream>>>(v, ln_v_g, ln_v_b, vfm);

    gemm_mfma<<<dim3(ED / 128, 1), 256, 0, stream>>>(re0b, wr0t, br0, r0, NZ, NZ, ED, NZ);

    sum_attn_split<<<dim3(BSZ * NH, NSPLIT), 256, 0, stream>>>(sqb, kfm, vfm, r0, rel_idx, po, pm, pl);

    k2v2_fused<<<BSZ * NH * SLEN, 64, 0, stream>>>(po, pm, pl, Wk2, bk2, Wv2, bv2,
                                                   ln_k2_g, ln_k2_b, ln_v2_g, ln_v2_b,
                                                   k2fm, v2fm);

    reg_attn_mfma<<<512, 256, 0, stream>>>(qb, kfm, vfm, k2fm, v2fm, r0, rel_idx, aob);

    gemm_fast<128><<<dim3(ED / 128, M / 128), 256, 0, stream>>>(
        aob, wot, bo, nullptr, nullptr, nullptr, (float*)d_out, nullptr, M, ED, ED, 0);
}

// Round 10
// 392.857 us; speedup vs baseline: 1.2128x; 1.2128x over previous
//
#include <hip/hip_runtime.h>
#include <cstdint>
#include <cstddef>

#define NH   16
#define HD   64
#define RLEN 2048
#define BSZ  2
#define SLEN 64
#define NZ   64
#define ED   1024
#define KTOT 2112   // SLEN + RLEN
#define NSPLIT 8    // sum_attn key splits
#define QSCALE 0.18033688011111374f   // 0.125 * log2(e) — softmax in log2 domain

typedef __bf16 bf16_t;
typedef bf16_t bf16x8 __attribute__((ext_vector_type(8)));
typedef bf16_t bf16x4 __attribute__((ext_vector_type(4)));
typedef float  f32x4  __attribute__((ext_vector_type(4)));

__device__ __forceinline__ f32x4 mfma16(bf16x8 a, bf16x8 b, f32x4 c) {
    return __builtin_amdgcn_mfma_f32_16x16x32_bf16(a, b, c, 0, 0, 0);
}

// async global->LDS DMA, 16B per lane (used by gemm_fast only)
__device__ __forceinline__ void dma16(const void* g, void* l) {
    __builtin_amdgcn_global_load_lds(
        (const __attribute__((address_space(1))) unsigned int*)g,
        (__attribute__((address_space(3))) unsigned int*)l, 16, 0, 0);
}

// Frag-major K layout per bh (PERMUTED keys: within a 64-key tile, MFMA
// group nt holds keys {4*l15+nt}):
//   off(key,d) = tile*4096 + (((key&3)*2 + (d>>5))*64 + ((d>>3)&3)*16 + ((key>>2)&15))*8 + (d&7)
// Frag-major V^T (natural key order): granule(dcol,key):
//   off(d,key) = tile*4096 + (((d>>4)*2 + (key>>5))*64 + ((key>>3)&3)*16 + (d&15))*8 + (key&7)

// ------------------------------------------------------------------
// m97-style GEMM: A bf16 [M][K], Bt bf16 [N][K]; BK=64, tile BM x 128,
// global_load_lds staging with XOR-swizzled granules.
// ------------------------------------------------------------------
template<int BM>
__global__ __launch_bounds__(256) void gemm_fast(
    const bf16_t* __restrict__ A, const bf16_t* __restrict__ Bt,
    const float* __restrict__ b0, const float* __restrict__ b1,
    const float* __restrict__ b2,
    bf16_t* __restrict__ oq, float* __restrict__ o1, float* __restrict__ o2,
    int M, int K, int N, int mode)
{
    constexpr int MT = BM / 64;
    __shared__ __align__(16) bf16_t As[BM * 64];
    __shared__ __align__(16) bf16_t Bs[128 * 64];

    const int t = threadIdx.x;
    const int wave = t >> 6, lane = t & 63;
    const int quad = lane >> 4, l15 = lane & 15;
    const int rsub = lane >> 3, gq = lane & 7;
    const int m0 = blockIdx.y * BM, n0 = blockIdx.x * 128;

    f32x4 acc[MT][8];
#pragma unroll
    for (int i = 0; i < MT; i++)
#pragma unroll
        for (int j = 0; j < 8; j++) acc[i][j] = (f32x4){0.f, 0.f, 0.f, 0.f};

    for (int k0 = 0; k0 < K; k0 += 64) {
#pragma unroll
        for (int j = 0; j < BM / 32; j++) {
            int row = wave * (BM / 4) + j * 8 + rsub;
            const bf16_t* g = A + (size_t)(m0 + row) * K + k0 + ((gq ^ (row & 7)) * 8);
            dma16(g, As + (wave * (BM / 4) + j * 8) * 64);
        }
#pragma unroll
        for (int j = 0; j < 4; j++) {
            int row = wave * 32 + j * 8 + rsub;
            const bf16_t* g = Bt + (size_t)(n0 + row) * K + k0 + ((gq ^ (row & 7)) * 8);
            dma16(g, Bs + (wave * 32 + j * 8) * 64);
        }
        __syncthreads();

#pragma unroll
        for (int kk = 0; kk < 2; kk++) {
            const int pg = ((kk * 4 + quad) ^ (l15 & 7)) * 8;
            bf16x8 af[MT], bf[8];
#pragma unroll
            for (int mt = 0; mt < MT; mt++)
                af[mt] = *(const bf16x8*)(As + (wave * (BM / 4) + mt * 16 + l15) * 64 + pg);
#pragma unroll
            for (int nt = 0; nt < 8; nt++)
                bf[nt] = *(const bf16x8*)(Bs + (nt * 16 + l15) * 64 + pg);
#pragma unroll
            for (int mt = 0; mt < MT; mt++)
#pragma unroll
                for (int nt = 0; nt < 8; nt++)
                    acc[mt][nt] = mfma16(af[mt], bf[nt], acc[mt][nt]);
        }
        __syncthreads();
    }

#pragma unroll
    for (int mt = 0; mt < MT; mt++)
#pragma unroll
        for (int nt = 0; nt < 8; nt++)
#pragma unroll
            for (int reg = 0; reg < 4; reg++) {
                int m = m0 + wave * (BM / 4) + mt * 16 + quad * 4 + reg;
                int n = n0 + nt * 16 + l15;
                if (mode == 0) {
                    o1[(size_t)m * N + n] = acc[mt][nt][reg] + b0[n];
                } else {
                    int seg = n >> 10, nl = n & 1023;
                    const float* bias = (seg == 0) ? b0 : (seg == 1) ? b1 : b2;
                    float c = acc[mt][nt][reg] + bias[nl];
                    int h = nl >> 6, d = nl & 63;
                    int r = m >> 1, bb = m & 1;
                    size_t off = (((size_t)bb * NH + h) * RLEN + r) * HD + d;
                    if (seg == 0)      oq[off] = (bf16_t)(c * QSCALE);
                    else if (seg == 1) o1[off] = c;
                    else               o2[off] = c;
                }
            }
}

// ------------------------------------------------------------------
// 64x128 MFMA GEMM (small r0 gemm only), padded LDS.
// ------------------------------------------------------------------
__global__ __launch_bounds__(256) void gemm_mfma(
    const bf16_t* __restrict__ A, const bf16_t* __restrict__ Bt,
    const float* __restrict__ bias, float* __restrict__ outf,
    int M, int K, int N, int Rr)
{
    constexpr int LDA = 40;
    __shared__ __align__(16) bf16_t As[64 * LDA];
    __shared__ __align__(16) bf16_t Bs[128 * LDA];

    const int t = threadIdx.x;
    const int wave = t >> 6, lane = t & 63;
    const int quad = lane >> 4, l15 = lane & 15;
    const int wrow = wave >> 1, wcol = wave & 1;
    const int m0 = blockIdx.y * 64, n0 = blockIdx.x * 128;

    f32x4 acc[2][4];
#pragma unroll
    for (int i = 0; i < 2; i++)
#pragma unroll
        for (int j = 0; j < 4; j++) acc[i][j] = (f32x4){0.f, 0.f, 0.f, 0.f};

    const int srow = t >> 2, sseg = (t & 3) * 8;

    for (int k0 = 0; k0 < K; k0 += 32) {
        bf16x8 av  = *(const bf16x8*)(A  + (size_t)(m0 + srow) * K + k0 + sseg);
        bf16x8 bv0 = *(const bf16x8*)(Bt + (size_t)(n0 + srow) * K + k0 + sseg);
        bf16x8 bv1 = *(const bf16x8*)(Bt + (size_t)(n0 + 64 + srow) * K + k0 + sseg);
        __syncthreads();
        *(bf16x8*)(As + srow * LDA + sseg)        = av;
        *(bf16x8*)(Bs + srow * LDA + sseg)        = bv0;
        *(bf16x8*)(Bs + (64 + srow) * LDA + sseg) = bv1;
        __syncthreads();

        bf16x8 af[2], bf[4];
#pragma unroll
        for (int mt = 0; mt < 2; mt++)
            af[mt] = *(const bf16x8*)(As + (wrow * 32 + mt * 16 + l15) * LDA + quad * 8);
#pragma unroll
        for (int nt = 0; nt < 4; nt++)
            bf[nt] = *(const bf16x8*)(Bs + (wcol * 64 + nt * 16 + l15) * LDA + quad * 8);
#pragma unroll
        for (int mt = 0; mt < 2; mt++)
#pragma unroll
            for (int nt = 0; nt < 4; nt++)
                acc[mt][nt] = mfma16(af[mt], bf[nt], acc[mt][nt]);
    }

#pragma unroll
    for (int mt = 0; mt < 2; mt++)
#pragma unroll
        for (int nt = 0; nt < 4; nt++)
#pragma unroll
            for (int reg = 0; reg < 4; reg++) {
                int m = m0 + wrow * 32 + mt * 16 + quad * 4 + reg;
                int n = n0 + wcol * 64 + nt * 16 + l15;
                if (m >= M) continue;
                float c = acc[mt][nt][reg] + bias[n];
                int h = n >> 6, d = n & 63;
                outf[(((size_t)h) * Rr + m) * HD + d] = c;   // [h][z][d]
            }
}

// ------------------------------------------------------------------
// K LayerNorm -> frag-major bf16 (PERMUTED keys). One wave per key row.
// ------------------------------------------------------------------
__global__ __launch_bounds__(256) void ln_k_frag(
    const float* __restrict__ x, const float* __restrict__ g, const float* __restrict__ b,
    bf16_t* __restrict__ kfm)
{
    int row  = blockIdx.x * 4 + (threadIdx.x >> 6);
    int lane = threadIdx.x & 63;
    float v = x[(size_t)row * HD + lane];
    float s1 = v, s2 = v * v;
#pragma unroll
    for (int o = 32; o > 0; o >>= 1) {
        s1 += __shfl_xor(s1, o);
        s2 += __shfl_xor(s2, o);
    }
    float mean = s1 * (1.f / 64.f);
    float var  = s2 * (1.f / 64.f) - mean * mean;
    float y = (v - mean) * rsqrtf(var + 1e-5f) * g[lane] + b[lane];
    int bh = row >> 11, r = row & 2047, d = lane;
    int rt = r & 63;
    size_t off = (size_t)bh * 131072 + (size_t)(r >> 6) * 4096 +
        (size_t)((((rt & 3) * 2 + (d >> 5)) * 64 + ((d >> 3) & 3) * 16 + (rt >> 2)) * 8 + (d & 7));
    kfm[off] = (bf16_t)y;
}

// ------------------------------------------------------------------
// V LayerNorm + transpose -> frag-major bf16 V^T (natural key order).
// ------------------------------------------------------------------
__global__ __launch_bounds__(256) void lnv_frag(
    const float* __restrict__ v, const float* __restrict__ g,
    const float* __restrict__ b, bf16_t* __restrict__ vfm)
{
    __shared__ float tile[64][65];
    const int bh = blockIdx.y, tidx = blockIdx.x;
    const int t = threadIdx.x;
    const int wave = t >> 6, lane = t & 63;

#pragma unroll
    for (int i = 0; i < 16; i++) {
        int rl = wave * 16 + i;
        float x = v[((size_t)bh * RLEN + tidx * 64 + rl) * HD + lane];
        float s1 = x, s2 = x * x;
#pragma unroll
        for (int o = 32; o > 0; o >>= 1) {
            s1 += __shfl_xor(s1, o);
            s2 += __shfl_xor(s2, o);
        }
        float mean = s1 * (1.f / 64.f);
        float var  = s2 * (1.f / 64.f) - mean * mean;
        tile[rl][lane] = (x - mean) * rsqrtf(var + 1e-5f) * g[lane] + b[lane];
    }
    __syncthreads();
    int d = t >> 2, rs = (t & 3) * 16;
    bf16x8 o0, o1;
#pragma unroll
    for (int j = 0; j < 8; j++) {
        o0[j] = (bf16_t)tile[rs + j][d];
        o1[j] = (bf16_t)tile[rs + 8 + j][d];
    }
    size_t base = (size_t)bh * 131072;
    size_t off0 = base + (size_t)((((tidx * 4 + (d >> 4)) * 2 + (rs >> 5)) * 64
                  + ((rs >> 3) & 3) * 16 + (d & 15)) * 8);
    int rs2 = rs + 8;
    size_t off1 = base + (size_t)((((tidx * 4 + (d >> 4)) * 2 + (rs2 >> 5)) * 64
                  + ((rs2 >> 3) & 3) * 16 + (d & 15)) * 8);
    *(bf16x8*)(vfm + off0) = o0;
    *(bf16x8*)(vfm + off1) = o1;
}

// ------------------------------------------------------------------
__global__ __launch_bounds__(256) void cvt_bf16(
    const float* __restrict__ src, bf16_t* __restrict__ dst, int n)
{
    int i = (blockIdx.x * 256 + threadIdx.x) * 4;
    if (i < n) {
        float4 v = *(const float4*)(src + i);
        bf16x4 o;
        o[0] = (bf16_t)v.x; o[1] = (bf16_t)v.y; o[2] = (bf16_t)v.z; o[3] = (bf16_t)v.w;
        *(bf16x4*)(dst + i) = o;
    }
}

// ------------------------------------------------------------------
// Prep kernel: batched weight transpose+cvt (bids 0..1039), sum_q
// gather (1040..1167), rel_emb0 cvt (1168..1171).
// ------------------------------------------------------------------
__global__ __launch_bounds__(256) void prep_batch(
    const float* __restrict__ Wq, const float* __restrict__ Wk,
    const float* __restrict__ Wv, const float* __restrict__ Wo,
    const float* __restrict__ Wr0,
    bf16_t* __restrict__ wqt, bf16_t* __restrict__ wkt,
    bf16_t* __restrict__ wvt, bf16_t* __restrict__ wot,
    bf16_t* __restrict__ wr0t,
    const float* __restrict__ emb, const int* __restrict__ ids,
    bf16_t* __restrict__ sum_q,
    const float* __restrict__ rel_emb0, bf16_t* __restrict__ re0b)
{
    const int bid = blockIdx.x;
    const int t = threadIdx.x;

    if (bid >= 1168) {          // rel_emb0 cvt (4096 elems)
        int i = ((bid - 1168) * 256 + t) * 4;
        float4 v = *(const float4*)(rel_emb0 + i);
        bf16x4 o;
        o[0] = (bf16_t)v.x; o[1] = (bf16_t)v.y; o[2] = (bf16_t)v.z; o[3] = (bf16_t)v.w;
        *(bf16x4*)(re0b + i) = o;
        return;
    }
    if (bid >= 1040) {          // sum_q gather (log2-domain scale)
        int sb = bid - 1040;
        int s = sb >> 1, b = sb & 1;
        int id = ids[b * SLEN + s];
        const float* src = emb + (size_t)id * ED;
        for (int e = t; e < ED; e += 256) {
            int h = e >> 6, d = e & 63;
            sum_q[(((size_t)b * NH + h) * SLEN + s) * HD + d] = (bf16_t)(src[e] * QSCALE);
        }
        return;
    }

    __shared__ float tile[64][65];
    const float* src; bf16_t* dst; int R, C, r0, c0;
    if (bid < 1024) {
        int sel = bid >> 8, local = bid & 255;
        src = (sel == 0) ? Wq : (sel == 1) ? Wk : (sel == 2) ? Wv : Wo;
        dst = (sel == 0) ? wqt : (sel == 1) ? wkt : (sel == 2) ? wvt : wot;
        R = ED; C = ED; r0 = (local >> 4) * 64; c0 = (local & 15) * 64;
    } else {
        src = Wr0; dst = wr0t; R = NZ; C = ED; r0 = 0; c0 = (bid - 1024) * 64;
    }
#pragma unroll
    for (int i = 0; i < 4; i++) {
        int idx = t + i * 256;
        int r = idx >> 4, c = (idx & 15) * 4;
        float4 vv = *(const float4*)(src + (size_t)(r0 + r) * C + c0 + c);
        tile[r][c] = vv.x; tile[r][c + 1] = vv.y; tile[r][c + 2] = vv.z; tile[r][c + 3] = vv.w;
    }
    __syncthreads();
    int cc = t >> 2, rs = (t & 3) * 16;
    bf16x8 o0, o1;
#pragma unroll
    for (int j = 0; j < 8; j++) {
        o0[j] = (bf16_t)tile[rs + j][cc];
        o1[j] = (bf16_t)tile[rs + 8 + j][cc];
    }
    *(bf16x8*)(dst + (size_t)(c0 + cc) * R + r0 + rs) = o0;
    *(bf16x8*)(dst + (size_t)(c0 + cc) * R + r0 + rs + 8) = o1;
}

// ------------------------------------------------------------------
// One 64-key attention tile for a wave owning MT*16 q-rows.
// Barrier-free. Softmax in log2 domain (scores pre-scaled by log2e):
// shared quad-group max, row sums via MFMA with all-ones B operand.
// ------------------------------------------------------------------
template<int MT>
__device__ __forceinline__ void attn_tile(
    const bf16_t* __restrict__ kt, const bf16_t* __restrict__ vt,
    const int* __restrict__ relbase, int koff, bool userel,
    const float* __restrict__ qrsw, bf16_t* __restrict__ Psw,
    const bf16x8 (&qf)[MT][2],
    f32x4 (&O)[MT][4], float& m_q, float (&l_i)[MT][4],
    int quad, int l15, int lane)
{
    bf16x8 kf[4][2];
#pragma unroll
    for (int nt = 0; nt < 4; nt++)
#pragma unroll
        for (int kb = 0; kb < 2; kb++)
            kf[nt][kb] = *(const bf16x8*)(kt + ((nt * 2 + kb) * 64 + lane) * 8);

    int4 crel[MT][4];
    if (userel) {
#pragma unroll
        for (int mt = 0; mt < MT; mt++)
#pragma unroll
            for (int reg = 0; reg < 4; reg++)
                crel[mt][reg] = *(const int4*)(relbase + (size_t)(mt * 16 + reg) * RLEN + koff);
    }

    f32x4 S[MT][4];
#pragma unroll
    for (int mt = 0; mt < MT; mt++)
#pragma unroll
        for (int nt = 0; nt < 4; nt++) {
            f32x4 acc = (f32x4){0.f, 0.f, 0.f, 0.f};
            acc = mfma16(qf[mt][0], kf[nt][0], acc);
            acc = mfma16(qf[mt][1], kf[nt][1], acc);
            S[mt][nt] = acc;
        }

    // V frags issued now (K regs dead) — latency hides under softmax
    bf16x8 vf[4][2];
#pragma unroll
    for (int nt = 0; nt < 4; nt++)
#pragma unroll
        for (int kb = 0; kb < 2; kb++)
            vf[nt][kb] = *(const bf16x8*)(vt + ((nt * 2 + kb) * 64 + lane) * 8);

    if (userel) {
#pragma unroll
        for (int mt = 0; mt < MT; mt++)
#pragma unroll
            for (int reg = 0; reg < 4; reg++) {
                const float* qr = qrsw + (mt * 16 + quad * 4 + reg) * 64;
                int4 c = crel[mt][reg];
                S[mt][0][reg] += qr[c.x];
                S[mt][1][reg] += qr[c.y];
                S[mt][2][reg] += qr[c.z];
                S[mt][3][reg] += qr[c.w];
            }
    }

    // shared quad-group max: one shuffle chain for all MT*4 rows
    float v = -1e30f;
#pragma unroll
    for (int mt = 0; mt < MT; mt++)
#pragma unroll
        for (int nt = 0; nt < 4; nt++) {
            f32x4 s = S[mt][nt];
            v = fmaxf(v, fmaxf(fmaxf(s[0], s[1]), fmaxf(s[2], s[3])));
        }
#pragma unroll
    for (int o = 8; o > 0; o >>= 1) v = fmaxf(v, __shfl_xor(v, o));
    float mnew = fmaxf(m_q, v);
    float alpha = exp2f(m_q - mnew);
    m_q = mnew;

#pragma unroll
    for (int mt = 0; mt < MT; mt++)
#pragma unroll
        for (int nt = 0; nt < 4; nt++)
#pragma unroll
            for (int reg = 0; reg < 4; reg++)
                S[mt][nt][reg] = exp2f(S[mt][nt][reg] - mnew);

#pragma unroll
    for (int mt = 0; mt < MT; mt++) {
#pragma unroll
        for (int nt = 0; nt < 4; nt++) {
            O[mt][nt][0] *= alpha; O[mt][nt][1] *= alpha;
            O[mt][nt][2] *= alpha; O[mt][nt][3] *= alpha;
        }
#pragma unroll
        for (int reg = 0; reg < 4; reg++) l_i[mt][reg] *= alpha;
    }

    // P -> LDS (4 consecutive keys per lane), PV + row-sum via MFMA-ones
    bf16x8 ones;
#pragma unroll
    for (int j = 0; j < 8; j++) ones[j] = (bf16_t)1.0f;

#pragma unroll
    for (int mt = 0; mt < MT; mt++)
#pragma unroll
        for (int reg = 0; reg < 4; reg++) {
            bf16x4 pv;
            pv[0] = (bf16_t)S[mt][0][reg]; pv[1] = (bf16_t)S[mt][1][reg];
            pv[2] = (bf16_t)S[mt][2][reg]; pv[3] = (bf16_t)S[mt][3][reg];
            *(bf16x4*)(Psw + (mt * 16 + quad * 4 + reg) * 72 + 4 * l15) = pv;
        }

#pragma unroll
    for (int mt = 0; mt < MT; mt++) {
        bf16x8 pf0 = *(const bf16x8*)(Psw + (mt * 16 + l15) * 72 + quad * 8);
        bf16x8 pf1 = *(const bf16x8*)(Psw + (mt * 16 + l15) * 72 + 32 + quad * 8);
        f32x4 ls = (f32x4){0.f, 0.f, 0.f, 0.f};
        ls = mfma16(pf0, ones, ls);
        ls = mfma16(pf1, ones, ls);
#pragma unroll
        for (int nt = 0; nt < 4; nt++) {
            O[mt][nt] = mfma16(pf0, vf[nt][0], O[mt][nt]);
            O[mt][nt] = mfma16(pf1, vf[nt][1], O[mt][nt]);
        }
#pragma unroll
        for (int reg = 0; reg < 4; reg++) l_i[mt][reg] += ls[reg];
    }
}

// build fp32 qr table rows (mt*16 + quad*4 + reg) for this wave
template<int MT>
__device__ __forceinline__ void build_qr(
    const float* __restrict__ r0, int h, const bf16x8 (&qf)[MT][2],
    float* __restrict__ qrsw, int quad, int l15)
{
#pragma unroll
    for (int nt = 0; nt < 4; nt++) {
        const float* rp = r0 + ((size_t)h * NZ + l15 + 16 * nt) * HD + quad * 8;
        float4 a0 = *(const float4*)(rp);
        float4 a1 = *(const float4*)(rp + 4);
        bf16x8 bf0;
        bf0[0] = (bf16_t)a0.x; bf0[1] = (bf16_t)a0.y; bf0[2] = (bf16_t)a0.z; bf0[3] = (bf16_t)a0.w;
        bf0[4] = (bf16_t)a1.x; bf0[5] = (bf16_t)a1.y; bf0[6] = (bf16_t)a1.z; bf0[7] = (bf16_t)a1.w;
        float4 b0 = *(const float4*)(rp + 32);
        float4 b1 = *(const float4*)(rp + 36);
        bf16x8 bf1;
        bf1[0] = (bf16_t)b0.x; bf1[1] = (bf16_t)b0.y; bf1[2] = (bf16_t)b0.z; bf1[3] = (bf16_t)b0.w;
        bf1[4] = (bf16_t)b1.x; bf1[5] = (bf16_t)b1.y; bf1[6] = (bf16_t)b1.z; bf1[7] = (bf16_t)b1.w;
#pragma unroll
        for (int mt = 0; mt < MT; mt++) {
            f32x4 qa = (f32x4){0.f, 0.f, 0.f, 0.f};
            qa = mfma16(qf[mt][0], bf0, qa);
            qa = mfma16(qf[mt][1], bf1, qa);
#pragma unroll
            for (int reg = 0; reg < 4; reg++)
                qrsw[(mt * 16 + quad * 4 + reg) * 64 + l15 + 16 * nt] = qa[reg];
        }
    }
}

// ------------------------------------------------------------------
// Summary attention, split-K, barrier-free. grid (32, NSPLIT).
// ------------------------------------------------------------------
__global__ __launch_bounds__(256) void sum_attn_split(
    const bf16_t* __restrict__ Qb,   // sum_q [bh][s][d] row-major
    const bf16_t* __restrict__ kfm, const bf16_t* __restrict__ vfm,
    const float*  __restrict__ r0,
    const int*    __restrict__ rel_idx,
    float* __restrict__ po, float* __restrict__ pm, float* __restrict__ pl)
{
    const int bh = blockIdx.x;
    const int split = blockIdx.y;
    const int b = bh >> 4, h = bh & 15;
    const int t = threadIdx.x;
    const int wave = t >> 6, lane = t & 63;
    const int quad = lane >> 4, l15 = lane & 15;

    __shared__ __align__(16) bf16_t Ps[4][16 * 72];
    __shared__ float qrs[4][16 * 64];

    bf16x8 qf[1][2];
    const bf16_t* Qrow = Qb + ((size_t)bh * SLEN + wave * 16 + l15) * HD;
    qf[0][0] = *(const bf16x8*)(Qrow + quad * 8);
    qf[0][1] = *(const bf16x8*)(Qrow + 32 + quad * 8);

    build_qr<1>(r0, h, qf, qrs[wave], quad, l15);

    f32x4 O[1][4];
    float m_q = -1e30f;
    float l_i[1][4];
#pragma unroll
    for (int nt = 0; nt < 4; nt++) O[0][nt] = (f32x4){0.f, 0.f, 0.f, 0.f};
#pragma unroll
    for (int r = 0; r < 4; r++) l_i[0][r] = 0.f;

    const int* relbase = rel_idx + ((size_t)b * KTOT + wave * 16 + quad * 4) * RLEN + 4 * l15;

    const bf16_t* kbase = kfm + (size_t)bh * 131072 + (size_t)(split * 4) * 4096;
    const bf16_t* vbase = vfm + (size_t)bh * 131072 + (size_t)(split * 4) * 4096;

    for (int i = 0; i < 4; i++) {
        const int koff = (split * 4 + i) * 64;
        attn_tile<1>(kbase + (size_t)i * 4096, vbase + (size_t)i * 4096,
                     relbase, koff, true, qrs[wave], Ps[wave], qf,
                     O, m_q, l_i, quad, l15, lane);
    }

    const size_t pslot = (size_t)bh * NSPLIT + split;
#pragma unroll
    for (int nt = 0; nt < 4; nt++)
#pragma unroll
        for (int reg = 0; reg < 4; reg++) {
            int sq = wave * 16 + quad * 4 + reg;
            po[(pslot * SLEN + sq) * HD + l15 + 16 * nt] = O[0][nt][reg];
        }
#pragma unroll
    for (int reg = 0; reg < 4; reg++) {
        int sq = wave * 16 + quad * 4 + reg;
        if (l15 == 0) {
            pm[pslot * SLEN + sq] = m_q;
            pl[pslot * SLEN + sq] = l_i[0][reg];
        }
    }
}

// ------------------------------------------------------------------
// Fused split-reduce + sum_k2/sum_v2 LN projections. One wave per
// (bh, s) row. grid 2048 x 64 threads. (pm is in log2 domain.)
// ------------------------------------------------------------------
__global__ __launch_bounds__(64) void k2v2_fused(
    const float* __restrict__ po, const float* __restrict__ pm,
    const float* __restrict__ pl,
    const float* __restrict__ Wk2, const float* __restrict__ bk2,
    const float* __restrict__ Wv2, const float* __restrict__ bv2,
    const float* __restrict__ gk, const float* __restrict__ bk,
    const float* __restrict__ gv, const float* __restrict__ bv,
    bf16_t* __restrict__ k2fm, bf16_t* __restrict__ v2fm)
{
    int row = blockIdx.x;              // bh*64 + s
    int d = threadIdx.x;
    int bh = row >> 6, s = row & 63;

    // reduce splits for this row (log2 domain)
    float M = -1e30f, mm[NSPLIT];
#pragma unroll
    for (int j = 0; j < NSPLIT; j++) {
        mm[j] = pm[((size_t)bh * NSPLIT + j) * SLEN + s];
        M = fmaxf(M, mm[j]);
    }
    float L = 0.f, acc = 0.f;
#pragma unroll
    for (int j = 0; j < NSPLIT; j++) {
        float a = exp2f(mm[j] - M);
        L += pl[((size_t)bh * NSPLIT + j) * SLEN + s] * a;
        acc += po[(((size_t)bh * NSPLIT + j) * SLEN + s) * HD + d] * a;
    }
    __shared__ float xs[64];
    xs[d] = acc / L;
    __syncthreads();

#pragma unroll
    for (int which = 0; which < 2; which++) {
        const float* W  = which ? Wv2 : Wk2;
        const float* bi = which ? bv2 : bk2;
        const float* g  = which ? gv : gk;
        const float* bb = which ? bv : bk;
        float a = bi[d];
#pragma unroll
        for (int j = 0; j < 64; j++) a += xs[j] * W[j * HD + d];
        float s1 = a, s2 = a * a;
#pragma unroll
        for (int o = 32; o > 0; o >>= 1) {
            s1 += __shfl_xor(s1, o);
            s2 += __shfl_xor(s2, o);
        }
        float mean = s1 * (1.f / 64.f);
        float var  = s2 * (1.f / 64.f) - mean * mean;
        float y = (a - mean) * rsqrtf(var + 1e-5f) * g[d] + bb[d];
        if (which == 0) {
            size_t off = (size_t)bh * 4096 +
                (size_t)((((s & 3) * 2 + (d >> 5)) * 64
                          + ((d >> 3) & 3) * 16 + (s >> 2)) * 8 + (d & 7));
            k2fm[off] = (bf16_t)y;
        } else {
            size_t off = (size_t)bh * 4096 +
                (size_t)((((d >> 4) * 2 + (s >> 5)) * 64
                          + ((s >> 3) & 3) * 16 + (d & 15)) * 8 + (s & 7));
            v2fm[off] = (bf16_t)y;
        }
    }
}

// ------------------------------------------------------------------
// Main attention, barrier-free MFMA flash. Each wave owns 32 q-rows
// (2 m-frags), streams all 33 key-tiles global->reg. grid 512.
// ------------------------------------------------------------------
__global__ __launch_bounds__(256) void reg_attn_mfma(
    const bf16_t* __restrict__ Qb,    // [bh][r][d] row-major
    const bf16_t* __restrict__ kfm, const bf16_t* __restrict__ vfm,
    const bf16_t* __restrict__ k2fm, const bf16_t* __restrict__ v2fm,
    const float*  __restrict__ r0,
    const int*    __restrict__ rel_idx,
    bf16_t* __restrict__ attn_out)    // [r][b][E] bf16
{
    const int bid = blockIdx.x;       // 512 = 8 XCD x 4 bh x 16 qtiles
    const int bh = (bid & 7) * 4 + ((bid >> 3) & 3);
    const int qt = bid >> 5;          // 0..15
    const int b = bh >> 4, h = bh & 15;
    const int q0 = qt * 128;

    const int t = threadIdx.x;
    const int wave = t >> 6, lane = t & 63;
    const int quad = lane >> 4, l15 = lane & 15;

    __shared__ __align__(16) bf16_t Ps[4][32 * 72];
    __shared__ float qrs[4][32 * 64];

    bf16x8 qf[2][2];
#pragma unroll
    for (int mt = 0; mt < 2; mt++) {
        const bf16_t* Qrow = Qb + ((size_t)bh * RLEN + q0 + wave * 32 + mt * 16 + l15) * HD;
        qf[mt][0] = *(const bf16x8*)(Qrow + quad * 8);
        qf[mt][1] = *(const bf16x8*)(Qrow + 32 + quad * 8);
    }

    build_qr<2>(r0, h, qf, qrs[wave], quad, l15);

    f32x4 O[2][4];
    float m_q = -1e30f;
    float l_i[2][4];
#pragma unroll
    for (int mt = 0; mt < 2; mt++)
#pragma unroll
        for (int nt = 0; nt < 4; nt++) O[mt][nt] = (f32x4){0.f, 0.f, 0.f, 0.f};
#pragma unroll
    for (int mt = 0; mt < 2; mt++)
#pragma unroll
        for (int r = 0; r < 4; r++) l_i[mt][r] = 0.f;

    const int* relbase = rel_idx +
        ((size_t)b * KTOT + SLEN + q0 + wave * 32 + quad * 4) * RLEN + 4 * l15;

    // summary tile (no rel bias), peeled
    attn_tile<2>(k2fm + (size_t)bh * 4096, v2fm + (size_t)bh * 4096,
                 relbase, 0, false, qrs[wave], Ps[wave], qf,
                 O, m_q, l_i, quad, l15, lane);

    const bf16_t* kt = kfm + (size_t)bh * 131072;
    const bf16_t* vt = vfm + (size_t)bh * 131072;
    for (int tile = 0; tile < 32; tile++) {
        attn_tile<2>(kt, vt, relbase, tile * 64, true,
                     qrs[wave], Ps[wave], qf, O, m_q, l_i, quad, l15, lane);
        kt += 4096; vt += 4096;
    }

#pragma unroll
    for (int mt = 0; mt < 2; mt++) {
        float linv[4];
#pragma unroll
        for (int reg = 0; reg < 4; reg++) linv[reg] = 1.0f / l_i[mt][reg];
#pragma unroll
        for (int nt = 0; nt < 4; nt++)
#pragma unroll
            for (int reg = 0; reg < 4; reg++) {
                int q = q0 + wave * 32 + mt * 16 + quad * 4 + reg;
                attn_out[((size_t)q * BSZ + b) * ED + h * HD + l15 + 16 * nt] =
                    (bf16_t)(O[mt][nt][reg] * linv[reg]);
            }
    }
}

// ------------------------------------------------------------------
extern "C" void kernel_launch(void* const* d_in, const int* in_sizes, int n_in,
                              void* d_out, int out_size, void* d_ws, size_t ws_size,
                              hipStream_t stream)
{
    const float* reg_x    = (const float*)d_in[0];
    const int*   sum_ids  = (const int*)d_in[1];
    const int*   rel_idx  = (const int*)d_in[2];
    const float* emb_sum  = (const float*)d_in[5];
    const float* rel_emb0 = (const float*)d_in[6];
    const float* Wq = (const float*)d_in[7];
    const float* bq = (const float*)d_in[8];
    const float* Wk = (const float*)d_in[9];
    const float* bk = (const float*)d_in[10];
    const float* Wv = (const float*)d_in[11];
    const float* bv = (const float*)d_in[12];
    const float* Wr0 = (const float*)d_in[13];
    const float* br0 = (const float*)d_in[14];
    const float* Wk2 = (const float*)d_in[15];
    const float* bk2 = (const float*)d_in[16];
    const float* Wv2 = (const float*)d_in[17];
    const float* bv2 = (const float*)d_in[18];
    const float* Wo  = (const float*)d_in[19];
    const float* bo  = (const float*)d_in[20];
    const float* ln_k_g  = (const float*)d_in[21];
    const float* ln_k_b  = (const float*)d_in[22];
    const float* ln_v_g  = (const float*)d_in[23];
    const float* ln_v_b  = (const float*)d_in[24];
    const float* ln_k2_g = (const float*)d_in[25];
    const float* ln_k2_b = (const float*)d_in[26];
    const float* ln_v2_g = (const float*)d_in[27];
    const float* ln_v2_b = (const float*)d_in[28];

    const size_t QKV = (size_t)BSZ * NH * RLEN * HD;   // 4,194,304
    const size_t SUM = (size_t)BSZ * NH * SLEN * HD;   // 131,072

    float* ws  = (float*)d_ws;
    float* k   = ws;                    // fp32 K; later aliased by aob
    float* v   = k + QKV;               // fp32 V
    float* r0  = v + QKV;

    bf16_t* xb   = (bf16_t*)(r0 + (size_t)NH * NZ * HD);  // dead after QKV -> po
    bf16_t* qb   = xb + QKV;
    bf16_t* kfm  = qb + QKV;
    bf16_t* vfm  = kfm + QKV;
    bf16_t* sqb  = vfm + QKV;
    bf16_t* k2fm = sqb + SUM;
    bf16_t* v2fm = k2fm + SUM;
    bf16_t* wqt  = v2fm + SUM;          // wqt|wkt|wvt contiguous [3072][1024]
    bf16_t* wkt  = wqt + (size_t)ED * ED;
    bf16_t* wvt  = wkt + (size_t)ED * ED;
    bf16_t* wot  = wvt + (size_t)ED * ED;
    bf16_t* wr0t = wot + (size_t)ED * ED;
    bf16_t* re0b = wr0t + (size_t)ED * NZ;
    bf16_t* aob  = (bf16_t*)k;
    float*  po   = (float*)xb;
    float*  pm   = po + (size_t)BSZ * NH * NSPLIT * SLEN * HD;
    float*  pl   = pm + (size_t)BSZ * NH * NSPLIT * SLEN;

    const int M = RLEN * BSZ;   // 4096

    cvt_bf16<<<(int)(QKV / 1024), 256, 0, stream>>>(reg_x, xb, (int)QKV);
    prep_batch<<<1172, 256, 0, stream>>>(Wq, Wk, Wv, Wo, Wr0,
                                         wqt, wkt, wvt, wot, wr0t,
                                         emb_sum, sum_ids, sqb, rel_emb0, re0b);

    gemm_fast<128><<<dim3(3 * ED / 128, M / 128), 256, 0, stream>>>(
        xb, wqt, bq, bk, bv, qb, k, v, M, ED, 3 * ED, 1);

    ln_k_frag<<<(BSZ * NH * RLEN) / 4, 256, 0, stream>>>(k, ln_k_g, ln_k_b, kfm);
    lnv_frag<<<dim3(RLEN / 64, BSZ * NH), 256, 0, stream>>>(v, ln_v_g, ln_v_b, vfm);

    gemm_mfma<<<dim3(ED / 128, 1), 256, 0, stream>>>(re0b, wr0t, br0, r0, NZ, NZ, ED, NZ);

    sum_attn_split<<<dim3(BSZ * NH, NSPLIT), 256, 0, stream>>>(sqb, kfm, vfm, r0, rel_idx, po, pm, pl);

    k2v2_fused<<<BSZ * NH * SLEN, 64, 0, stream>>>(po, pm, pl, Wk2, bk2, Wv2, bv2,
                                                   ln_k2_g, ln_k2_b, ln_v2_g, ln_v2_b,
                                                   k2fm, v2fm);

    reg_attn_mfma<<<512, 256, 0, stream>>>(qb, kfm, vfm, k2fm, v2fm, r0, rel_idx, aob);

    gemm_fast<128><<<dim3(ED / 128, M / 128), 256, 0, stream>>>(
        aob, wot, bo, nullptr, nullptr, nullptr, (float*)d_out, nullptr, M, ED, ED, 0);
}